// Round 6
// baseline (710.946 us; speedup 1.0000x reference)
//
#include <hip/hip_runtime.h>
#include <hip/hip_bf16.h>
#include <cstdint>

#define B_   2
#define T_   4096
#define D_   1024
#define H_   16
#define DH_  64
#define M_   (B_*T_)     // 8192 rows
#define K3_  (3*D_)      // 3072
#define TC_  128         // cumsum chunk
#define NCH_ (T_/TC_)    // 32 chunks

typedef __attribute__((ext_vector_type(4))) float  f32x4;
typedef __attribute__((ext_vector_type(8))) short  short8;

__device__ __forceinline__ float bf2f(ushort u) {
    union { uint32_t i; float f; } v; v.i = ((uint32_t)u) << 16; return v.f;
}
__device__ __forceinline__ ushort f2bf(float f) {
    union { float f; uint32_t i; } v; v.f = f;
    uint32_t r = v.i + 0x7FFF + ((v.i >> 16) & 1);
    return (ushort)(r >> 16);
}

template<bool F32>
__device__ __forceinline__ float ld_in(const void* p, size_t i) {
    if (F32) return ((const float*)p)[i];
    return bf2f(((const ushort*)p)[i]);
}

// store helpers: bf16 internal buffers vs f32 final output
__device__ __forceinline__ void st_c(ushort* p, float v) { *p = f2bf(v); }
__device__ __forceinline__ void st_c(float*  p, float v) { *p = v; }

#define GLOAD_LDS16(g, l) \
    __builtin_amdgcn_global_load_lds((const __attribute__((address_space(1))) void*)(g), \
                                     (__attribute__((address_space(3))) void*)(l), 16, 0, 0)

// ---------------- P0: dtype detector ----------------
__global__ void detect_kernel(const ushort* __restrict__ xu, int* __restrict__ flag) {
    __shared__ int cnt;
    if (threadIdx.x == 0) cnt = 0;
    __syncthreads();
    int c = 0;
    for (int i = threadIdx.x; i < 16384; i += 256) {
        ushort u = xu[i];
        if ((u & 0x7F80) == 0x7F80) c++;
    }
    if (c) atomicAdd(&cnt, c);
    __syncthreads();
    if (threadIdx.x == 0) flag[0] = (cnt > 0) ? 1 : 0;
}

// ---------------- P1: gates  g9[row][p*3+c] ----------------
template<bool F32>
__device__ __forceinline__ void gates_body(const void* x,
                                           const void* Wg_q, const void* bg_q,
                                           const void* Wg_k, const void* bg_k,
                                           const void* Wg_v, const void* bg_v,
                                           float* __restrict__ g9) {
    const int wave = threadIdx.x >> 6, lane = threadIdx.x & 63;
    const int row  = blockIdx.x * 4 + wave;
    const size_t xoff = (size_t)row * D_;
    float acc[9] = {0,0,0,0,0,0,0,0,0};
    for (int d = lane; d < D_; d += 64) {
        float xv = ld_in<F32>(x, xoff + d);
        #pragma unroll
        for (int c = 0; c < 3; c++) {
            acc[0+c] += xv * ld_in<F32>(Wg_q, d*3+c);
            acc[3+c] += xv * ld_in<F32>(Wg_k, d*3+c);
            acc[6+c] += xv * ld_in<F32>(Wg_v, d*3+c);
        }
    }
    #pragma unroll
    for (int i = 0; i < 9; i++) {
        #pragma unroll
        for (int o = 32; o >= 1; o >>= 1) acc[i] += __shfl_xor(acc[i], o, 64);
    }
    const void* bgs[3] = {bg_q, bg_k, bg_v};
    float g[9];
    #pragma unroll
    for (int p = 0; p < 3; p++) {
        float l0 = acc[p*3+0] + ld_in<F32>(bgs[p], 0);
        float l1 = acc[p*3+1] + ld_in<F32>(bgs[p], 1);
        float l2 = acc[p*3+2] + ld_in<F32>(bgs[p], 2);
        float mx = fmaxf(l0, fmaxf(l1, l2));
        float e0 = expf(l0-mx), e1 = expf(l1-mx), e2 = expf(l2-mx);
        float s  = e0+e1+e2;
        float g0 = fminf(e0/s, 0.6f), g1 = fminf(e1/s, 0.6f), g2 = fminf(e2/s, 0.6f);
        float s2 = g0+g1+g2;
        g[p*3+0] = g0/s2; g[p*3+1] = g1/s2; g[p*3+2] = g2/s2;
    }
    if (lane == 0) {
        #pragma unroll
        for (int i = 0; i < 9; i++) g9[(size_t)row*9 + i] = g[i];
    }
}
__global__ void gates_kernel(const void* x,
                             const void* Wg_q, const void* bg_q,
                             const void* Wg_k, const void* bg_k,
                             const void* Wg_v, const void* bg_v,
                             const int* __restrict__ flag, float* __restrict__ g9) {
    if (flag[0]) gates_body<true >(x, Wg_q, bg_q, Wg_k, bg_k, Wg_v, bg_v, g9);
    else         gates_body<false>(x, Wg_q, bg_q, Wg_k, bg_k, Wg_v, bg_v, g9);
}

// ---------------- P2: per-chunk sums ----------------
template<bool F32>
__device__ __forceinline__ void chunk_sum_body(const void* x, float* __restrict__ part) {
    const int d = blockIdx.x * 256 + threadIdx.x;
    const int tc = blockIdx.y, b = blockIdx.z;
    const size_t base = ((size_t)b*T_ + (size_t)tc*TC_) * D_ + d;
    float s = 0.f;
    for (int i = 0; i < TC_; i++) s += ld_in<F32>(x, base + (size_t)i * D_);
    part[((size_t)b*NCH_ + tc) * D_ + d] = s;
}
__global__ void chunk_sum_kernel(const void* x, const int* __restrict__ flag,
                                 float* __restrict__ part) {
    if (flag[0]) chunk_sum_body<true >(x, part);
    else         chunk_sum_body<false>(x, part);
}

// ---------------- P3: exclusive scan of chunk sums ----------------
__global__ void scan_part_kernel(float* __restrict__ part) {
    const int idx = blockIdx.x * 256 + threadIdx.x;   // 0..2047
    const int b = idx >> 10, d = idx & (D_-1);
    float run = 0.f;
    for (int tc = 0; tc < NCH_; tc++) {
        size_t o = ((size_t)b*NCH_ + tc) * D_ + d;
        float v = part[o]; part[o] = run; run += v;
    }
}

// ---------------- P4: build UNSCALED concat input Xc[row] = [x | integ | deriv] ----------------
// gates folded into the GEMM accumulator per K-segment instead (3x less traffic).
template<bool F32>
__device__ __forceinline__ void build_xs_body(const void* x, const float* __restrict__ part,
                                              ushort* __restrict__ Xc) {
    const int d0 = (blockIdx.x * 256 + threadIdx.x) * 2;
    const int tc = blockIdx.y, b = blockIdx.z;
    const int t0 = tc * TC_;
    float carry0 = part[((size_t)b*NCH_ + tc) * D_ + d0];
    float carry1 = part[((size_t)b*NCH_ + tc) * D_ + d0 + 1];
    const size_t xbase = ((size_t)b*T_ + t0) * D_ + d0;
    float prev0 = (t0 > 0) ? ld_in<F32>(x, xbase - D_)     : 0.0f;
    float prev1 = (t0 > 0) ? ld_in<F32>(x, xbase - D_ + 1) : 0.0f;
    for (int i = 0; i < TC_; i++) {
        const int t = t0 + i;
        float xv0 = ld_in<F32>(x, xbase + (size_t)i * D_);
        float xv1 = ld_in<F32>(x, xbase + (size_t)i * D_ + 1);
        carry0 += xv0; carry1 += xv1;
        const float rinv = 1.0f / (float)(t + 1);
        float in0 = carry0 * rinv, in1 = carry1 * rinv;
        float de0 = (t == 0) ? 0.0f : (xv0 - prev0);
        float de1 = (t == 0) ? 0.0f : (xv1 - prev1);
        prev0 = xv0; prev1 = xv1;
        const size_t base = ((size_t)b*T_ + t) * K3_ + d0;
        *(ushort2*)(Xc + base       ) = make_ushort2(f2bf(xv0), f2bf(xv1));
        *(ushort2*)(Xc + base +   D_) = make_ushort2(f2bf(in0), f2bf(in1));
        *(ushort2*)(Xc + base + 2*D_) = make_ushort2(f2bf(de0), f2bf(de1));
    }
}
__global__ void build_xs_kernel(const void* x, const float* __restrict__ part,
                                const int* __restrict__ flag, ushort* __restrict__ Xc) {
    if (flag[0]) build_xs_body<true >(x, part, Xc);
    else         build_xs_body<false>(x, part, Xc);
}

// ---------------- P5: weight transpose -> (N,K) bf16 ----------------
struct WPtrs { const void* w[10]; };
template<bool F32>
__device__ __forceinline__ void transpose_w_body(WPtrs ptrs, ushort* __restrict__ Wt,
                                                 ushort* __restrict__ WoT) {
    const int z = blockIdx.z;                 // 0..8: W{p,j}; 9: Wo
    const void* src = ptrs.w[z];
    __shared__ float tile[32][33];
    const int tx = threadIdx.x & 31, ty = threadIdx.x >> 5;
    const int d0 = blockIdx.x * 32, c0 = blockIdx.y * 32;
    #pragma unroll
    for (int i = 0; i < 4; i++) {
        int r = ty + i*8;
        tile[r][tx] = ld_in<F32>(src, (size_t)(d0 + r) * D_ + c0 + tx);
    }
    __syncthreads();
    if (z < 9) {
        const int p = z / 3, j = z % 3;
        #pragma unroll
        for (int i = 0; i < 4; i++) {
            int r = ty + i*8;
            Wt[(size_t)(p*D_ + c0 + r) * K3_ + j*D_ + d0 + tx] = f2bf(tile[tx][r]);
        }
    } else {
        #pragma unroll
        for (int i = 0; i < 4; i++) {
            int r = ty + i*8;
            WoT[(size_t)(c0 + r) * D_ + d0 + tx] = f2bf(tile[tx][r]);
        }
    }
}
__global__ void transpose_w_kernel(WPtrs ptrs, const int* __restrict__ flag,
                                   ushort* __restrict__ Wt, ushort* __restrict__ WoT) {
    if (flag[0]) transpose_w_body<true >(ptrs, Wt, WoT);
    else         transpose_w_body<false>(ptrs, Wt, WoT);
}

// ---------------- GEMM: C(MxN) = A(MxK,row) * Bt(NxK,row)^T, bf16 in, f32 acc
// BK=64, XOR-swizzled LDS granules, GM=16 grid grouping (XCD L2 locality).
// GATED: K split into 3 segments of 1024; segment accumulator accS folded into
// accT scaled by per-row gate g9[row][p*3+seg] (p = nt>>3). This lets A be the
// single unscaled [x|i|d] concat (one copy, 3x less fetch).
template<typename CT, int NT, bool GATED>
__global__ __launch_bounds__(256) void gemm_bt_kernel(
        const ushort* __restrict__ Abase,
        const ushort* __restrict__ Bt,
        CT* __restrict__ C,
        const float* __restrict__ g9,
        int K, int lda, int ldc) {
    __shared__ __align__(16) ushort As[128*64];
    __shared__ __align__(16) ushort Bs[128*64];
    const int tid  = threadIdx.x;
    const int lane = tid & 63;
    const int wave = tid >> 6;

    const int gid = blockIdx.x;
    const int grp = gid / (16*NT);
    const int rem = gid % (16*NT);
    const int mt  = grp*16 + (rem & 15);
    const int nt  = rem >> 4;
    const int m0 = mt * 128;
    const int n0 = nt * 128;
    const int p  = nt >> 3;              // projection (GATED only)

    // staging: 4 rounds each for A and B; round g covers granules g*256+tid
    const ushort* agp[4]; const ushort* bgp[4];
    ushort* alp[4]; ushort* blp[4];
    #pragma unroll
    for (int g = 0; g < 4; g++) {
        const int I   = g*256 + tid;         // LDS granule index
        const int row = I >> 3;              // 0..127
        const int c8  = (I & 7) ^ (row & 7); // global k-granule (swizzle inverse)
        agp[g] = Abase + (size_t)(m0 + row) * lda + c8*8;
        bgp[g] = Bt    + (size_t)(n0 + row) * K   + c8*8;
        alp[g] = As + (size_t)I * 8;
        blp[g] = Bs + (size_t)I * 8;
    }

    const int wm = wave & 1, wn = wave >> 1;
    const int quad = lane >> 4, l16 = lane & 15;
    const int sw = l16 & 7;

    f32x4 accS[4][4] = {};   // segment accumulator (MFMA target)
    f32x4 accT[4][4] = {};   // gated total (VALU folded); unused when !GATED

    const int NSEG = GATED ? 3 : 1;
    const int SEG  = K / NSEG;
    for (int seg = 0; seg < NSEG; seg++) {
        for (int kt = seg*SEG; kt < (seg+1)*SEG; kt += 64) {
            #pragma unroll
            for (int g = 0; g < 4; g++) GLOAD_LDS16(agp[g] + kt, alp[g]);
            #pragma unroll
            for (int g = 0; g < 4; g++) GLOAD_LDS16(bgp[g] + kt, blp[g]);
            __syncthreads();
            #pragma unroll
            for (int kk = 0; kk < 2; kk++) {
                short8 af[4], bfr[4];
                #pragma unroll
                for (int i = 0; i < 4; i++) {
                    const int r = wm*64 + i*16 + l16;
                    af[i]  = *(const short8*)(As + (size_t)(r*8 + ((quad + kk*4) ^ sw)) * 8);
                }
                #pragma unroll
                for (int j = 0; j < 4; j++) {
                    const int r = wn*64 + j*16 + l16;
                    bfr[j] = *(const short8*)(Bs + (size_t)(r*8 + ((quad + kk*4) ^ sw)) * 8);
                }
                #pragma unroll
                for (int i = 0; i < 4; i++)
                    #pragma unroll
                    for (int j = 0; j < 4; j++)
                        accS[i][j] = __builtin_amdgcn_mfma_f32_16x16x32_bf16(af[i], bfr[j], accS[i][j], 0, 0, 0);
            }
            __syncthreads();
        }
        if (GATED) {
            // fold segment into total with per-row gate; rows per m89/m91 C-layout
            #pragma unroll
            for (int i = 0; i < 4; i++) {
                float gv[4];
                #pragma unroll
                for (int rg = 0; rg < 4; rg++) {
                    const int rrow = m0 + wm*64 + i*16 + quad*4 + rg;
                    gv[rg] = g9[(size_t)rrow * 9 + p*3 + seg];
                }
                #pragma unroll
                for (int j = 0; j < 4; j++)
                    #pragma unroll
                    for (int rg = 0; rg < 4; rg++) {
                        accT[i][j][rg] += gv[rg] * accS[i][j][rg];
                        if (seg < 2) accS[i][j][rg] = 0.0f;
                    }
            }
        }
    }
    // epilogue: C/D layout col=lane&15, row=quad*4+reg  [m89/m91 verified]
    #pragma unroll
    for (int i = 0; i < 4; i++) {
        #pragma unroll
        for (int j = 0; j < 4; j++) {
            const int rrow = m0 + wm*64 + i*16 + quad*4;
            const int col  = n0 + wn*64 + j*16 + l16;
            #pragma unroll
            for (int rg = 0; rg < 4; rg++)
                st_c(&C[(size_t)(rrow + rg) * ldc + col],
                     GATED ? accT[i][j][rg] : accS[i][j][rg]);
        }
    }
}

// ---------------- attention: one block per (b,t), all 16 heads ----------------
__global__ __launch_bounds__(256) void attn_kernel(const ushort* __restrict__ QKV,
                                                   ushort* __restrict__ AO) {
    const int tid = threadIdx.x;
    const int bt  = blockIdx.x;              // b*T_ + t
    const int t   = bt & (T_-1);
    const size_t qrow = (size_t)bt * K3_;
    const int e0 = tid * 4;

    const ushort4 q4 = *(const ushort4*)(QKV + qrow + e0);
    const float qf0 = bf2f(q4.x), qf1 = bf2f(q4.y), qf2 = bf2f(q4.z), qf3 = bf2f(q4.w);

    float sc[14];
    #pragma unroll
    for (int a = 0; a < 14; a++) {
        const int off = (a <= 3) ? a : (1 << (a - 2));
        float p = -1e30f;
        if (off <= t) {                      // block-uniform
            const ushort4 k4 = *(const ushort4*)(QKV + qrow - (size_t)off*K3_ + D_ + e0);
            float pp = qf0*bf2f(k4.x) + qf1*bf2f(k4.y) + qf2*bf2f(k4.z) + qf3*bf2f(k4.w);
            pp += __shfl_xor(pp, 1, 64);
            pp += __shfl_xor(pp, 2, 64);
            pp += __shfl_xor(pp, 4, 64);
            pp += __shfl_xor(pp, 8, 64);
            p = pp * 0.125f;                 // DH^-0.5
        }
        sc[a] = p;
    }
    float mx = -1e30f;
    #pragma unroll
    for (int a = 0; a < 14; a++) mx = fmaxf(mx, sc[a]);
    float ev[14], s = 0.0f;
    #pragma unroll
    for (int a = 0; a < 14; a++) { ev[a] = (sc[a] > -1e29f) ? expf(sc[a] - mx) : 0.0f; s += ev[a]; }
    const float rs = 1.0f / s;

    float a0 = 0.f, a1 = 0.f, a2 = 0.f, a3 = 0.f;
    #pragma unroll
    for (int a = 0; a < 14; a++) {
        const int off = (a <= 3) ? a : (1 << (a - 2));
        if (off <= t) {
            const ushort4 v4 = *(const ushort4*)(QKV + qrow - (size_t)off*K3_ + 2*D_ + e0);
            const float w = ev[a] * rs;
            a0 += w * bf2f(v4.x); a1 += w * bf2f(v4.y);
            a2 += w * bf2f(v4.z); a3 += w * bf2f(v4.w);
        }
    }
    ushort* dst = AO + (size_t)bt * D_ + e0;
    dst[0] = f2bf(a0); dst[1] = f2bf(a1); dst[2] = f2bf(a2); dst[3] = f2bf(a3);
}

extern "C" void kernel_launch(void* const* d_in, const int* in_sizes, int n_in,
                              void* d_out, int out_size, void* d_ws, size_t ws_size,
                              hipStream_t stream) {
    (void)in_sizes; (void)n_in; (void)out_size; (void)ws_size;
    const void* x    = d_in[0];
    const void* Wg_q = d_in[4];  const void* bg_q = d_in[5];
    const void* Wg_k = d_in[9];  const void* bg_k = d_in[10];
    const void* Wg_v = d_in[14]; const void* bg_v = d_in[15];

    char* ws = (char*)d_ws;
    int*    flag = (int*)ws;    ws += 16;
    float*  g9   = (float*)ws;  ws += (size_t)M_*9*4;            //   0.3 MB
    float*  part = (float*)ws;  ws += (size_t)B_*NCH_*D_*4;      //   0.26 MB
    ushort* Wt   = (ushort*)ws; ws += (size_t)K3_*K3_*2;         //  18 MB
    ushort* WoT  = (ushort*)ws; ws += (size_t)D_*D_*2;           //   2 MB
    ushort* Xc   = (ushort*)ws; ws += (size_t)M_*K3_*2;          //  50 MB (unscaled concat)
    ushort* QKV  = (ushort*)ws; ws += (size_t)M_*K3_*2;          //  50 MB
    ushort* AO   = (ushort*)ws; ws += (size_t)M_*D_*2;           //  17 MB  (total ~140 MB)

    detect_kernel<<<1, 256, 0, stream>>>((const ushort*)x, flag);
    gates_kernel<<<M_/4, 256, 0, stream>>>(x, Wg_q, bg_q, Wg_k, bg_k, Wg_v, bg_v, flag, g9);
    chunk_sum_kernel<<<dim3(D_/256, NCH_, B_), 256, 0, stream>>>(x, flag, part);
    scan_part_kernel<<<(B_*D_)/256, 256, 0, stream>>>(part);
    WPtrs wp;
    wp.w[0] = d_in[1];  wp.w[1] = d_in[2];  wp.w[2] = d_in[3];
    wp.w[3] = d_in[6];  wp.w[4] = d_in[7];  wp.w[5] = d_in[8];
    wp.w[6] = d_in[11]; wp.w[7] = d_in[12]; wp.w[8] = d_in[13];
    wp.w[9] = d_in[16];
    transpose_w_kernel<<<dim3(32, 32, 10), 256, 0, stream>>>(wp, flag, Wt, WoT);
    build_xs_kernel<<<dim3(D_/512, NCH_, B_), 256, 0, stream>>>(x, part, flag, Xc);
    // QKV: gated GEMM, M=8192, N=3072 (3 projections x 1024), K=3072 in 3 segments
    gemm_bt_kernel<ushort, 24, true><<<24*64, 256, 0, stream>>>(Xc, Wt, QKV, g9, K3_, K3_, K3_);
    attn_kernel<<<B_*T_, 256, 0, stream>>>(QKV, AO);
    // out = AO @ Wo : M=8192, N=1024, K=1024  (f32 out, ungated)
    gemm_bt_kernel<float, 8, false><<<8*64, 256, 0, stream>>>(AO, WoT, (float*)d_out, nullptr, D_, D_, D_);
}

// Round 7
// 546.491 us; speedup vs baseline: 1.3009x; 1.3009x over previous
//
#include <hip/hip_runtime.h>
#include <hip/hip_bf16.h>
#include <cstdint>

#define B_   2
#define T_   4096
#define D_   1024
#define H_   16
#define DH_  64
#define M_   (B_*T_)     // 8192 rows
#define K3_  (3*D_)      // 3072
#define TC_  128         // cumsum chunk
#define NCH_ (T_/TC_)    // 32 chunks

typedef __attribute__((ext_vector_type(4))) float  f32x4;
typedef __attribute__((ext_vector_type(8))) short  short8;

__device__ __forceinline__ float bf2f(ushort u) {
    union { uint32_t i; float f; } v; v.i = ((uint32_t)u) << 16; return v.f;
}
__device__ __forceinline__ ushort f2bf(float f) {
    union { float f; uint32_t i; } v; v.f = f;
    uint32_t r = v.i + 0x7FFF + ((v.i >> 16) & 1);
    return (ushort)(r >> 16);
}

template<bool F32>
__device__ __forceinline__ float ld_in(const void* p, size_t i) {
    if (F32) return ((const float*)p)[i];
    return bf2f(((const ushort*)p)[i]);
}

// store helpers: bf16 internal buffers vs f32 final output
__device__ __forceinline__ void st_c(ushort* p, float v) { *p = f2bf(v); }
__device__ __forceinline__ void st_c(float*  p, float v) { *p = v; }

#define GLOAD_LDS16(g, l) \
    __builtin_amdgcn_global_load_lds((const __attribute__((address_space(1))) void*)(g), \
                                     (__attribute__((address_space(3))) void*)(l), 16, 0, 0)

// ---------------- P0: dtype detector ----------------
__global__ void detect_kernel(const ushort* __restrict__ xu, int* __restrict__ flag) {
    __shared__ int cnt;
    if (threadIdx.x == 0) cnt = 0;
    __syncthreads();
    int c = 0;
    for (int i = threadIdx.x; i < 16384; i += 256) {
        ushort u = xu[i];
        if ((u & 0x7F80) == 0x7F80) c++;
    }
    if (c) atomicAdd(&cnt, c);
    __syncthreads();
    if (threadIdx.x == 0) flag[0] = (cnt > 0) ? 1 : 0;
}

// ---------------- P1: gates -> telescoping chain ratios ----------------
// g9[row][p*3+s] stores: s=0: g0/g1', s=1: g1'/g2', s=2: g2'  (g'=max(g,1e-30))
// GEMM multiplies acc by ratio after each K-segment -> net coeffs g0,g1',g2'
// with a SINGLE accumulator (round-6's dual-acc cost 160 VGPR -> occupancy cliff).
template<bool F32>
__device__ __forceinline__ void gates_body(const void* x,
                                           const void* Wg_q, const void* bg_q,
                                           const void* Wg_k, const void* bg_k,
                                           const void* Wg_v, const void* bg_v,
                                           float* __restrict__ g9) {
    const int wave = threadIdx.x >> 6, lane = threadIdx.x & 63;
    const int row  = blockIdx.x * 4 + wave;
    const size_t xoff = (size_t)row * D_;
    float acc[9] = {0,0,0,0,0,0,0,0,0};
    for (int d = lane; d < D_; d += 64) {
        float xv = ld_in<F32>(x, xoff + d);
        #pragma unroll
        for (int c = 0; c < 3; c++) {
            acc[0+c] += xv * ld_in<F32>(Wg_q, d*3+c);
            acc[3+c] += xv * ld_in<F32>(Wg_k, d*3+c);
            acc[6+c] += xv * ld_in<F32>(Wg_v, d*3+c);
        }
    }
    #pragma unroll
    for (int i = 0; i < 9; i++) {
        #pragma unroll
        for (int o = 32; o >= 1; o >>= 1) acc[i] += __shfl_xor(acc[i], o, 64);
    }
    const void* bgs[3] = {bg_q, bg_k, bg_v};
    float g[9];
    #pragma unroll
    for (int p = 0; p < 3; p++) {
        float l0 = acc[p*3+0] + ld_in<F32>(bgs[p], 0);
        float l1 = acc[p*3+1] + ld_in<F32>(bgs[p], 1);
        float l2 = acc[p*3+2] + ld_in<F32>(bgs[p], 2);
        float mx = fmaxf(l0, fmaxf(l1, l2));
        float e0 = expf(l0-mx), e1 = expf(l1-mx), e2 = expf(l2-mx);
        float s  = e0+e1+e2;
        float g0 = fminf(e0/s, 0.6f), g1 = fminf(e1/s, 0.6f), g2 = fminf(e2/s, 0.6f);
        float s2 = g0+g1+g2;
        g0 /= s2; g1 /= s2; g2 /= s2;
        float g1c = fmaxf(g1, 1e-30f), g2c = fmaxf(g2, 1e-30f);
        g[p*3+0] = g0 / g1c;
        g[p*3+1] = g1c / g2c;
        g[p*3+2] = g2c;
    }
    if (lane == 0) {
        #pragma unroll
        for (int i = 0; i < 9; i++) g9[(size_t)row*9 + i] = g[i];
    }
}
__global__ void gates_kernel(const void* x,
                             const void* Wg_q, const void* bg_q,
                             const void* Wg_k, const void* bg_k,
                             const void* Wg_v, const void* bg_v,
                             const int* __restrict__ flag, float* __restrict__ g9) {
    if (flag[0]) gates_body<true >(x, Wg_q, bg_q, Wg_k, bg_k, Wg_v, bg_v, g9);
    else         gates_body<false>(x, Wg_q, bg_q, Wg_k, bg_k, Wg_v, bg_v, g9);
}

// ---------------- P2: per-chunk sums ----------------
template<bool F32>
__device__ __forceinline__ void chunk_sum_body(const void* x, float* __restrict__ part) {
    const int d = blockIdx.x * 256 + threadIdx.x;
    const int tc = blockIdx.y, b = blockIdx.z;
    const size_t base = ((size_t)b*T_ + (size_t)tc*TC_) * D_ + d;
    float s = 0.f;
    for (int i = 0; i < TC_; i++) s += ld_in<F32>(x, base + (size_t)i * D_);
    part[((size_t)b*NCH_ + tc) * D_ + d] = s;
}
__global__ void chunk_sum_kernel(const void* x, const int* __restrict__ flag,
                                 float* __restrict__ part) {
    if (flag[0]) chunk_sum_body<true >(x, part);
    else         chunk_sum_body<false>(x, part);
}

// ---------------- P3: exclusive scan of chunk sums ----------------
__global__ void scan_part_kernel(float* __restrict__ part) {
    const int idx = blockIdx.x * 256 + threadIdx.x;   // 0..2047
    const int b = idx >> 10, d = idx & (D_-1);
    float run = 0.f;
    for (int tc = 0; tc < NCH_; tc++) {
        size_t o = ((size_t)b*NCH_ + tc) * D_ + d;
        float v = part[o]; part[o] = run; run += v;
    }
}

// ---------------- P4: build UNSCALED concat input Xc[row] = [x | integ | deriv] ----------------
template<bool F32>
__device__ __forceinline__ void build_xs_body(const void* x, const float* __restrict__ part,
                                              ushort* __restrict__ Xc) {
    const int d0 = (blockIdx.x * 256 + threadIdx.x) * 2;
    const int tc = blockIdx.y, b = blockIdx.z;
    const int t0 = tc * TC_;
    float carry0 = part[((size_t)b*NCH_ + tc) * D_ + d0];
    float carry1 = part[((size_t)b*NCH_ + tc) * D_ + d0 + 1];
    const size_t xbase = ((size_t)b*T_ + t0) * D_ + d0;
    float prev0 = (t0 > 0) ? ld_in<F32>(x, xbase - D_)     : 0.0f;
    float prev1 = (t0 > 0) ? ld_in<F32>(x, xbase - D_ + 1) : 0.0f;
    for (int i = 0; i < TC_; i++) {
        const int t = t0 + i;
        float xv0 = ld_in<F32>(x, xbase + (size_t)i * D_);
        float xv1 = ld_in<F32>(x, xbase + (size_t)i * D_ + 1);
        carry0 += xv0; carry1 += xv1;
        const float rinv = 1.0f / (float)(t + 1);
        float in0 = carry0 * rinv, in1 = carry1 * rinv;
        float de0 = (t == 0) ? 0.0f : (xv0 - prev0);
        float de1 = (t == 0) ? 0.0f : (xv1 - prev1);
        prev0 = xv0; prev1 = xv1;
        const size_t base = ((size_t)b*T_ + t) * K3_ + d0;
        *(ushort2*)(Xc + base       ) = make_ushort2(f2bf(xv0), f2bf(xv1));
        *(ushort2*)(Xc + base +   D_) = make_ushort2(f2bf(in0), f2bf(in1));
        *(ushort2*)(Xc + base + 2*D_) = make_ushort2(f2bf(de0), f2bf(de1));
    }
}
__global__ void build_xs_kernel(const void* x, const float* __restrict__ part,
                                const int* __restrict__ flag, ushort* __restrict__ Xc) {
    if (flag[0]) build_xs_body<true >(x, part, Xc);
    else         build_xs_body<false>(x, part, Xc);
}

// ---------------- P5: weight transpose -> (N,K) bf16 ----------------
struct WPtrs { const void* w[10]; };
template<bool F32>
__device__ __forceinline__ void transpose_w_body(WPtrs ptrs, ushort* __restrict__ Wt,
                                                 ushort* __restrict__ WoT) {
    const int z = blockIdx.z;                 // 0..8: W{p,j}; 9: Wo
    const void* src = ptrs.w[z];
    __shared__ float tile[32][33];
    const int tx = threadIdx.x & 31, ty = threadIdx.x >> 5;
    const int d0 = blockIdx.x * 32, c0 = blockIdx.y * 32;
    #pragma unroll
    for (int i = 0; i < 4; i++) {
        int r = ty + i*8;
        tile[r][tx] = ld_in<F32>(src, (size_t)(d0 + r) * D_ + c0 + tx);
    }
    __syncthreads();
    if (z < 9) {
        const int p = z / 3, j = z % 3;
        #pragma unroll
        for (int i = 0; i < 4; i++) {
            int r = ty + i*8;
            Wt[(size_t)(p*D_ + c0 + r) * K3_ + j*D_ + d0 + tx] = f2bf(tile[tx][r]);
        }
    } else {
        #pragma unroll
        for (int i = 0; i < 4; i++) {
            int r = ty + i*8;
            WoT[(size_t)(c0 + r) * D_ + d0 + tx] = f2bf(tile[tx][r]);
        }
    }
}
__global__ void transpose_w_kernel(WPtrs ptrs, const int* __restrict__ flag,
                                   ushort* __restrict__ Wt, ushort* __restrict__ WoT) {
    if (flag[0]) transpose_w_body<true >(ptrs, Wt, WoT);
    else         transpose_w_body<false>(ptrs, Wt, WoT);
}

// ---------------- GEMM: C(MxN) = A(MxK,row) * Bt(NxK,row)^T, bf16 in, f32 acc
// BK=64, XOR-swizzled LDS granules, GM=16 grid grouping (XCD L2 locality).
// GATED: single accumulator; after each 1024-K segment, acc *= chain-ratio
// g9[row][p*3+seg] (telescoping product -> per-segment gate coefficients).
template<typename CT, int NT, bool GATED>
__global__ __launch_bounds__(256) void gemm_bt_kernel(
        const ushort* __restrict__ Abase,
        const ushort* __restrict__ Bt,
        CT* __restrict__ C,
        const float* __restrict__ g9,
        int K, int lda, int ldc) {
    __shared__ __align__(16) ushort As[128*64];
    __shared__ __align__(16) ushort Bs[128*64];
    const int tid  = threadIdx.x;
    const int lane = tid & 63;
    const int wave = tid >> 6;

    const int gid = blockIdx.x;
    const int grp = gid / (16*NT);
    const int rem = gid % (16*NT);
    const int mt  = grp*16 + (rem & 15);
    const int nt  = rem >> 4;
    const int m0 = mt * 128;
    const int n0 = nt * 128;
    const int p  = nt >> 3;              // projection (GATED only)

    // staging: 4 rounds each for A and B; round g covers granules g*256+tid
    const ushort* agp[4]; const ushort* bgp[4];
    ushort* alp[4]; ushort* blp[4];
    #pragma unroll
    for (int g = 0; g < 4; g++) {
        const int I   = g*256 + tid;         // LDS granule index
        const int row = I >> 3;              // 0..127
        const int c8  = (I & 7) ^ (row & 7); // global k-granule (swizzle inverse)
        agp[g] = Abase + (size_t)(m0 + row) * lda + c8*8;
        bgp[g] = Bt    + (size_t)(n0 + row) * K   + c8*8;
        alp[g] = As + (size_t)I * 8;
        blp[g] = Bs + (size_t)I * 8;
    }

    const int wm = wave & 1, wn = wave >> 1;
    const int quad = lane >> 4, l16 = lane & 15;
    const int sw = l16 & 7;

    f32x4 acc[4][4] = {};

    const int NSEG = GATED ? 3 : 1;
    const int SEG  = K / NSEG;
    for (int seg = 0; seg < NSEG; seg++) {
        for (int kt = seg*SEG; kt < (seg+1)*SEG; kt += 64) {
            #pragma unroll
            for (int g = 0; g < 4; g++) GLOAD_LDS16(agp[g] + kt, alp[g]);
            #pragma unroll
            for (int g = 0; g < 4; g++) GLOAD_LDS16(bgp[g] + kt, blp[g]);
            __syncthreads();
            #pragma unroll
            for (int kk = 0; kk < 2; kk++) {
                short8 af[4], bfr[4];
                #pragma unroll
                for (int i = 0; i < 4; i++) {
                    const int r = wm*64 + i*16 + l16;
                    af[i]  = *(const short8*)(As + (size_t)(r*8 + ((quad + kk*4) ^ sw)) * 8);
                }
                #pragma unroll
                for (int j = 0; j < 4; j++) {
                    const int r = wn*64 + j*16 + l16;
                    bfr[j] = *(const short8*)(Bs + (size_t)(r*8 + ((quad + kk*4) ^ sw)) * 8);
                }
                #pragma unroll
                for (int i = 0; i < 4; i++)
                    #pragma unroll
                    for (int j = 0; j < 4; j++)
                        acc[i][j] = __builtin_amdgcn_mfma_f32_16x16x32_bf16(af[i], bfr[j], acc[i][j], 0, 0, 0);
            }
            __syncthreads();
        }
        if (GATED) {
            // telescoping fold: acc *= ratio[row, seg]; rows per m89/m91 C-layout
            #pragma unroll
            for (int i = 0; i < 4; i++) {
                float gv[4];
                #pragma unroll
                for (int rg = 0; rg < 4; rg++) {
                    const int rrow = m0 + wm*64 + i*16 + quad*4 + rg;
                    gv[rg] = g9[(size_t)rrow * 9 + p*3 + seg];
                }
                #pragma unroll
                for (int j = 0; j < 4; j++)
                    #pragma unroll
                    for (int rg = 0; rg < 4; rg++)
                        acc[i][j][rg] *= gv[rg];
            }
        }
    }
    // epilogue: C/D layout col=lane&15, row=quad*4+reg  [m89/m91 verified]
    #pragma unroll
    for (int i = 0; i < 4; i++) {
        #pragma unroll
        for (int j = 0; j < 4; j++) {
            const int rrow = m0 + wm*64 + i*16 + quad*4;
            const int col  = n0 + wn*64 + j*16 + l16;
            #pragma unroll
            for (int rg = 0; rg < 4; rg++)
                st_c(&C[(size_t)(rrow + rg) * ldc + col], acc[i][j][rg]);
        }
    }
}

// ---------------- attention: one block per (b,t), all 16 heads ----------------
__global__ __launch_bounds__(256) void attn_kernel(const ushort* __restrict__ QKV,
                                                   ushort* __restrict__ AO) {
    const int tid = threadIdx.x;
    const int bt  = blockIdx.x;              // b*T_ + t
    const int t   = bt & (T_-1);
    const size_t qrow = (size_t)bt * K3_;
    const int e0 = tid * 4;

    const ushort4 q4 = *(const ushort4*)(QKV + qrow + e0);
    const float qf0 = bf2f(q4.x), qf1 = bf2f(q4.y), qf2 = bf2f(q4.z), qf3 = bf2f(q4.w);

    float sc[14];
    #pragma unroll
    for (int a = 0; a < 14; a++) {
        const int off = (a <= 3) ? a : (1 << (a - 2));
        float p = -1e30f;
        if (off <= t) {                      // block-uniform
            const ushort4 k4 = *(const ushort4*)(QKV + qrow - (size_t)off*K3_ + D_ + e0);
            float pp = qf0*bf2f(k4.x) + qf1*bf2f(k4.y) + qf2*bf2f(k4.z) + qf3*bf2f(k4.w);
            pp += __shfl_xor(pp, 1, 64);
            pp += __shfl_xor(pp, 2, 64);
            pp += __shfl_xor(pp, 4, 64);
            pp += __shfl_xor(pp, 8, 64);
            p = pp * 0.125f;                 // DH^-0.5
        }
        sc[a] = p;
    }
    float mx = -1e30f;
    #pragma unroll
    for (int a = 0; a < 14; a++) mx = fmaxf(mx, sc[a]);
    float ev[14], s = 0.0f;
    #pragma unroll
    for (int a = 0; a < 14; a++) { ev[a] = (sc[a] > -1e29f) ? expf(sc[a] - mx) : 0.0f; s += ev[a]; }
    const float rs = 1.0f / s;

    float a0 = 0.f, a1 = 0.f, a2 = 0.f, a3 = 0.f;
    #pragma unroll
    for (int a = 0; a < 14; a++) {
        const int off = (a <= 3) ? a : (1 << (a - 2));
        if (off <= t) {
            const ushort4 v4 = *(const ushort4*)(QKV + qrow - (size_t)off*K3_ + 2*D_ + e0);
            const float w = ev[a] * rs;
            a0 += w * bf2f(v4.x); a1 += w * bf2f(v4.y);
            a2 += w * bf2f(v4.z); a3 += w * bf2f(v4.w);
        }
    }
    ushort* dst = AO + (size_t)bt * D_ + e0;
    dst[0] = f2bf(a0); dst[1] = f2bf(a1); dst[2] = f2bf(a2); dst[3] = f2bf(a3);
}

extern "C" void kernel_launch(void* const* d_in, const int* in_sizes, int n_in,
                              void* d_out, int out_size, void* d_ws, size_t ws_size,
                              hipStream_t stream) {
    (void)in_sizes; (void)n_in; (void)out_size; (void)ws_size;
    const void* x    = d_in[0];
    const void* Wg_q = d_in[4];  const void* bg_q = d_in[5];
    const void* Wg_k = d_in[9];  const void* bg_k = d_in[10];
    const void* Wg_v = d_in[14]; const void* bg_v = d_in[15];

    char* ws = (char*)d_ws;
    int*    flag = (int*)ws;    ws += 16;
    float*  g9   = (float*)ws;  ws += (size_t)M_*9*4;            //   0.3 MB
    float*  part = (float*)ws;  ws += (size_t)B_*NCH_*D_*4;      //   0.26 MB
    ushort* Wt   = (ushort*)ws; ws += (size_t)K3_*K3_*2;         //  18 MB
    ushort* WoT  = (ushort*)ws; ws += (size_t)D_*D_*2;           //   2 MB
    ushort* Xc   = (ushort*)ws; ws += (size_t)M_*K3_*2;          //  50 MB (unscaled concat)
    ushort* QKV  = (ushort*)ws; ws += (size_t)M_*K3_*2;          //  50 MB
    ushort* AO   = (ushort*)ws; ws += (size_t)M_*D_*2;           //  17 MB  (total ~140 MB)

    detect_kernel<<<1, 256, 0, stream>>>((const ushort*)x, flag);
    gates_kernel<<<M_/4, 256, 0, stream>>>(x, Wg_q, bg_q, Wg_k, bg_k, Wg_v, bg_v, flag, g9);
    chunk_sum_kernel<<<dim3(D_/256, NCH_, B_), 256, 0, stream>>>(x, flag, part);
    scan_part_kernel<<<(B_*D_)/256, 256, 0, stream>>>(part);
    WPtrs wp;
    wp.w[0] = d_in[1];  wp.w[1] = d_in[2];  wp.w[2] = d_in[3];
    wp.w[3] = d_in[6];  wp.w[4] = d_in[7];  wp.w[5] = d_in[8];
    wp.w[6] = d_in[11]; wp.w[7] = d_in[12]; wp.w[8] = d_in[13];
    wp.w[9] = d_in[16];
    transpose_w_kernel<<<dim3(32, 32, 10), 256, 0, stream>>>(wp, flag, Wt, WoT);
    build_xs_kernel<<<dim3(D_/512, NCH_, B_), 256, 0, stream>>>(x, part, flag, Xc);
    // QKV: gated GEMM, M=8192, N=3072 (3 projections x 1024), K=3072 in 3 segments
    gemm_bt_kernel<ushort, 24, true><<<24*64, 256, 0, stream>>>(Xc, Wt, QKV, g9, K3_, K3_, K3_);
    attn_kernel<<<B_*T_, 256, 0, stream>>>(QKV, AO);
    // out = AO @ Wo : M=8192, N=1024, K=1024  (f32 out, ungated)
    gemm_bt_kernel<float, 8, false><<<8*64, 256, 0, stream>>>(AO, WoT, (float*)d_out, nullptr, D_, D_, D_);
}